// Round 3
// baseline (700.593 us; speedup 1.0000x reference)
//
#include <hip/hip_runtime.h>
#include <stdint.h>

#define SLEN 2048
#define BSZ  2
#define HSZ  1024
#define FFND 4096
#define NEXP 8
#define TOPK 2
#define NTOK (SLEN*BSZ)        // 4096
#define NSLOT (NTOK*TOPK)      // 8192

#define BM 128
#define BN 128
#define BK 32
#define SPLITK 2               // gemm2 split-K factor
#define KS (FFND / SPLITK)     // 2048 per split

using short8 = __attribute__((ext_vector_type(8))) short;
using f32x4  = __attribute__((ext_vector_type(4))) float;

typedef __attribute__((address_space(1))) const unsigned int gu32;
typedef __attribute__((address_space(3))) unsigned int lu32;

__device__ inline void async_copy16(const void* g, void* l){
  // DMA 16B/lane global->LDS; LDS dest = wave-uniform base + lane*16
  __builtin_amdgcn_global_load_lds((gu32*)g, (lu32*)l, 16, 0, 0);
}

__device__ inline unsigned short f2bf(float f){
  unsigned u = __builtin_bit_cast(unsigned, f);
  u += 0x7FFFu + ((u >> 16) & 1u);      // round-to-nearest-even
  return (unsigned short)(u >> 16);
}

__device__ inline float gelu_tanh(float x){
  // jax.nn.gelu default (approximate=True)
  float u = 0.7978845608028654f * (x + 0.044715f * x * x * x);
  return 0.5f * x * (1.0f + tanhf(u));
}

// ---------------- routing kernels ----------------

__global__ void k_count(const int* __restrict__ ei, int* __restrict__ counts){
  int i = blockIdx.x * blockDim.x + threadIdx.x;
  if (i < NSLOT) atomicAdd(&counts[ei[i]], 1);
}

__global__ void k_scan(const int* __restrict__ counts, int* __restrict__ offsets,
                       int* __restrict__ fill){
  if (threadIdx.x == 0 && blockIdx.x == 0){
    int acc = 0;
    for (int e = 0; e < NEXP; e++){ offsets[e] = acc; fill[e] = acc; acc += counts[e]; }
  }
}

__global__ void k_assign(const int* __restrict__ ei, const float* __restrict__ ew,
                         int* __restrict__ fill, int* __restrict__ rowT,
                         float* __restrict__ rowC){
  int i = blockIdx.x * blockDim.x + threadIdx.x;
  if (i < NSLOT){
    int e = ei[i];
    int slot = atomicAdd(&fill[e], 1);
    rowT[slot] = i >> 1;       // token index (i = t*TOPK + k)
    rowC[slot] = ew[i];
  }
}

__global__ void k_gather(const float* __restrict__ x, const int* __restrict__ rowT,
                         unsigned short* __restrict__ Xg){
  int slot = blockIdx.x;
  int t = rowT[slot];
  int c = threadIdx.x * 4;
  float4 v = *(const float4*)(x + (size_t)t * HSZ + c);
  ushort4 o;
  o.x = f2bf(v.x); o.y = f2bf(v.y); o.z = f2bf(v.z); o.w = f2bf(v.w);
  *(ushort4*)(Xg + (size_t)slot * HSZ + c) = o;
}

// ------- merged weight transform: fp32 [R][C] -> bf16 [C][R], w1 & w2 -------
__global__ __launch_bounds__(256) void k_transpose2(const float* __restrict__ w1,
                                                    const float* __restrict__ w2,
                                                    unsigned short* __restrict__ Wt1,
                                                    unsigned short* __restrict__ Wt2){
  __shared__ unsigned short tile[64][65];
  const int tid = threadIdx.x;
  int z = blockIdx.y;
  const float* src; unsigned short* dst; int R, C, r0, c0;
  if (z < NEXP){
    src = w1 + (size_t)z * HSZ * FFND; dst = Wt1 + (size_t)z * HSZ * FFND;
    R = HSZ; C = FFND;
    c0 = (blockIdx.x & 63) * 64; r0 = (blockIdx.x >> 6) * 64;
  } else {
    z -= NEXP;
    src = w2 + (size_t)z * FFND * HSZ; dst = Wt2 + (size_t)z * FFND * HSZ;
    R = FFND; C = HSZ;
    c0 = (blockIdx.x & 15) * 64; r0 = (blockIdx.x >> 4) * 64;
  }
  #pragma unroll
  for (int p = 0; p < 4; p++){
    int r  = p * 16 + (tid >> 4);
    int cc = (tid & 15) * 4;
    float4 v = *(const float4*)(src + (size_t)(r0 + r) * C + c0 + cc);
    tile[r][cc]   = f2bf(v.x);
    tile[r][cc+1] = f2bf(v.y);
    tile[r][cc+2] = f2bf(v.z);
    tile[r][cc+3] = f2bf(v.w);
  }
  __syncthreads();
  #pragma unroll
  for (int p = 0; p < 4; p++){
    int c  = p * 16 + (tid >> 4);
    int rr = (tid & 15) * 4;
    ushort4 o;
    o.x = tile[rr][c]; o.y = tile[rr+1][c]; o.z = tile[rr+2][c]; o.w = tile[rr+3][c];
    *(ushort4*)(dst + (size_t)(c0 + c) * R + r0 + rr) = o;
  }
}

// ---------------- GEMM core (m97 recipe) ----------------
// A: bf16 [rows x K] k-contiguous, lda elems. B: bf16 [N x K] k-contiguous
// (pre-offset to row n0 and k-base), ldb elems. Unpadded 128x32 LDS tiles,
// global_load_lds staging, ds_read_b128 frags. 4 waves 2x2, 4x4 of 16x16x32.
__device__ inline void gemm_core(const unsigned short* __restrict__ Ag, int lda, int rows,
                                 const unsigned short* __restrict__ Bg, int ldb, int K,
                                 unsigned short* As, unsigned short* Bs,
                                 f32x4 acc[4][4])
{
  const int tid  = threadIdx.x;
  const int lane = tid & 63;
  const int wid  = tid >> 6;
  const int wm   = (wid & 1) * 64;
  const int wn   = (wid >> 1) * 64;
  const int q    = lane >> 4;
  const int l16  = lane & 15;

  for (int k0 = 0; k0 < K; k0 += BK){
    #pragma unroll
    for (int p = 0; p < 2; p++){
      int c  = (wid * 2 + p) * 64 + lane;   // chunk id, 16B each
      int r  = c >> 2;
      int kp = (c & 3) * 8;
      int ra = min(r, rows - 1);            // clamp tail (epilogue masks)
      async_copy16(Ag + (size_t)ra * lda + k0 + kp, As + (wid * 2 + p) * 512);
      async_copy16(Bg + (size_t)r  * ldb + k0 + kp, Bs + (wid * 2 + p) * 512);
    }
    __syncthreads();   // drains vmcnt before LDS use

    short8 af[4], bfr[4];
    #pragma unroll
    for (int i = 0; i < 4; i++)
      af[i] = *(const short8*)(As + (wm + i * 16 + l16) * BK + q * 8);
    #pragma unroll
    for (int j = 0; j < 4; j++)
      bfr[j] = *(const short8*)(Bs + (wn + j * 16 + l16) * BK + q * 8);

    #pragma unroll
    for (int i = 0; i < 4; i++)
      #pragma unroll
      for (int j = 0; j < 4; j++)
        acc[i][j] = __builtin_amdgcn_mfma_f32_16x16x32_bf16(af[i], bfr[j], acc[i][j], 0, 0, 0);
    __syncthreads();
  }
}

// ---------------- GEMM1: H = gelu(Xg @ Wt1[e]^T) ----------------
__global__ __launch_bounds__(256) void k_gemm1(const unsigned short* __restrict__ Xg,
                                               const unsigned short* __restrict__ Wt1,
                                               unsigned short* __restrict__ H,
                                               const int* __restrict__ counts,
                                               const int* __restrict__ offsets)
{
  __shared__ unsigned short smem[BM * BK + BN * BK];   // As | Bs, reused as epi scratch
  unsigned short* As = smem;
  unsigned short* Bs = smem + BM * BK;
  const int e    = blockIdx.z;
  const int cnt  = counts[e];
  const int mblk = blockIdx.y;
  if (mblk * BM >= cnt) return;
  const int n0   = blockIdx.x * BN;
  const int row0 = offsets[e] + mblk * BM;
  const int rows = min(BM, cnt - mblk * BM);

  f32x4 acc[4][4] = {};
  gemm_core(Xg + (size_t)row0 * HSZ, HSZ, rows,
            Wt1 + (size_t)e * HSZ * FFND + (size_t)n0 * HSZ, HSZ, HSZ, As, Bs, acc);

  const int lane = threadIdx.x & 63, wid = threadIdx.x >> 6;
  const int wm = (wid & 1) * 64, wn = (wid >> 1) * 64;
  const int q = lane >> 4, l16 = lane & 15;

  // per-wave LDS repack: 16x64 bf16 subtile (stride 68 to spread banks),
  // then b128 read-back + dwordx4 global stores. Scratch is wave-private.
  unsigned short* scr = smem + wid * (16 * 68);   // 4 * 2176 B = 8704 <= 16384
  #pragma unroll
  for (int i = 0; i < 4; i++){
    #pragma unroll
    for (int j = 0; j < 4; j++)
      #pragma unroll
      for (int r = 0; r < 4; r++)
        scr[(q * 4 + r) * 68 + j * 16 + l16] = f2bf(gelu_tanh(acc[i][j][r]));
    #pragma unroll
    for (int p = 0; p < 2; p++){
      int rr = p * 8 + (lane >> 3);
      int cc = (lane & 7) * 8;
      short8 v = *(const short8*)(scr + rr * 68 + cc);
      int grow = wm + i * 16 + rr;
      if (grow < rows)
        *(short8*)(H + (size_t)(row0 + grow) * FFND + n0 + wn + cc) = v;
    }
  }
}

// -------- GEMM2 (split-K): out[t] += coef * (H @ Wt2[e]^T) partial --------
__global__ __launch_bounds__(256) void k_gemm2(const unsigned short* __restrict__ H,
                                               const unsigned short* __restrict__ Wt2,
                                               float* __restrict__ out,
                                               const int* __restrict__ counts,
                                               const int* __restrict__ offsets,
                                               const int* __restrict__ rowT,
                                               const float* __restrict__ rowC)
{
  __shared__ unsigned short As[BM * BK];
  __shared__ unsigned short Bs[BN * BK];
  const int e    = blockIdx.z >> 1;      // expert
  const int s    = blockIdx.z & 1;       // K-split
  const int cnt  = counts[e];
  const int mblk = blockIdx.y;
  if (mblk * BM >= cnt) return;
  const int n0   = blockIdx.x * BN;
  const int row0 = offsets[e] + mblk * BM;
  const int rows = min(BM, cnt - mblk * BM);

  f32x4 acc[4][4] = {};
  gemm_core(H + (size_t)row0 * FFND + (size_t)s * KS, FFND, rows,
            Wt2 + (size_t)e * FFND * HSZ + (size_t)n0 * FFND + (size_t)s * KS,
            FFND, KS, As, Bs, acc);

  const int lane = threadIdx.x & 63, wid = threadIdx.x >> 6;
  const int wm = (wid & 1) * 64, wn = (wid >> 1) * 64;
  const int q = lane >> 4, l16 = lane & 15;
  #pragma unroll
  for (int i = 0; i < 4; i++)
    #pragma unroll
    for (int j = 0; j < 4; j++)
      #pragma unroll
      for (int r = 0; r < 4; r++){
        int row = wm + i * 16 + q * 4 + r;
        if (row < rows){
          int g = row0 + row;
          int col = wn + j * 16 + l16;
          atomicAdd(out + (size_t)rowT[g] * HSZ + n0 + col, rowC[g] * acc[i][j][r]);
        }
      }
}

// ---------------- launch ----------------
static inline size_t align_up(size_t v, size_t a){ return (v + a - 1) & ~(a - 1); }

extern "C" void kernel_launch(void* const* d_in, const int* in_sizes, int n_in,
                              void* d_out, int out_size, void* d_ws, size_t ws_size,
                              hipStream_t stream) {
  const float* x  = (const float*)d_in[0];
  const float* ew = (const float*)d_in[1];
  const int*   ei = (const int*)d_in[2];
  const float* w1 = (const float*)d_in[3];
  const float* w2 = (const float*)d_in[4];
  float* out = (float*)d_out;

  // workspace layout (bytes)
  char* base = (char*)d_ws;
  size_t off = 0;
  int* counts  = (int*)(base + off); off += 64;
  int* fill    = (int*)(base + off); off += 64;
  int* offsets = (int*)(base + off); off = align_up(off + 64, 4096);
  int* rowT    = (int*)(base + off); off += (size_t)NSLOT * 4;
  float* rowC  = (float*)(base + off); off = align_up(off + (size_t)NSLOT * 4, 1 << 20);
  unsigned short* Xg  = (unsigned short*)(base + off); off = align_up(off + (size_t)NSLOT * HSZ * 2, 1 << 20);
  unsigned short* H   = (unsigned short*)(base + off); off = align_up(off + (size_t)NSLOT * FFND * 2, 1 << 20);
  unsigned short* Wt1 = (unsigned short*)(base + off); off = align_up(off + (size_t)NEXP * HSZ * FFND * 2, 1 << 20);
  unsigned short* Wt2 = (unsigned short*)(base + off); off += (size_t)NEXP * FFND * HSZ * 2;
  (void)ws_size;

  hipMemsetAsync(d_out, 0, (size_t)out_size * sizeof(float), stream);
  hipMemsetAsync(counts, 0, 64, stream);

  k_count <<<NSLOT / 256, 256, 0, stream>>>(ei, counts);
  k_scan  <<<1, 64, 0, stream>>>(counts, offsets, fill);
  k_assign<<<NSLOT / 256, 256, 0, stream>>>(ei, ew, fill, rowT, rowC);
  k_gather<<<NSLOT, 256, 0, stream>>>(x, rowT, Xg);

  // merged weight transform: z<8 -> w1 [HSZ][FFND]->Wt1; z>=8 -> w2 -> Wt2
  k_transpose2<<<dim3(1024, 2 * NEXP), 256, 0, stream>>>(w1, w2, Wt1, Wt2);

  // worst case one expert owns all 8192 rows -> 64 m-blocks; extras early-exit
  k_gemm1<<<dim3(FFND / BN, 64, NEXP), 256, 0, stream>>>(Xg, Wt1, H, counts, offsets);
  k_gemm2<<<dim3(HSZ / BN, 64, NEXP * SPLITK), 256, 0, stream>>>(H, Wt2, out, counts, offsets, rowT, rowC);
}

// Round 4
// 629.907 us; speedup vs baseline: 1.1122x; 1.1122x over previous
//
#include <hip/hip_runtime.h>
#include <stdint.h>

#define SLEN 2048
#define BSZ  2
#define HSZ  1024
#define FFND 4096
#define NEXP 8
#define TOPK 2
#define NTOK (SLEN*BSZ)        // 4096
#define NSLOT (NTOK*TOPK)      // 8192

#define BM 128
#define BK 64                  // two BK=32 sub-tiles per operand

using short8 = __attribute__((ext_vector_type(8))) short;
using f32x4  = __attribute__((ext_vector_type(4))) float;

typedef __attribute__((address_space(1))) const unsigned int gu32;
typedef __attribute__((address_space(3))) unsigned int lu32;

__device__ inline void async_copy16(const void* g, void* l){
  // DMA 16B/lane global->LDS; LDS dest = wave-uniform base + lane*16
  __builtin_amdgcn_global_load_lds((gu32*)g, (lu32*)l, 16, 0, 0);
}

__device__ inline unsigned short f2bf(float f){
  unsigned u = __builtin_bit_cast(unsigned, f);
  u += 0x7FFFu + ((u >> 16) & 1u);      // round-to-nearest-even
  return (unsigned short)(u >> 16);
}

__device__ inline float gelu_tanh(float x){
  // jax.nn.gelu default (approximate=True)
  float u = 0.7978845608028654f * (x + 0.044715f * x * x * x);
  return 0.5f * x * (1.0f + tanhf(u));
}

// ---------------- fused routing: count + scan + assign (one block) ----------
__global__ __launch_bounds__(1024) void k_route(const int* __restrict__ ei,
                                                const float* __restrict__ ew,
                                                int* __restrict__ counts,
                                                int* __restrict__ offsets,
                                                int* __restrict__ rowT,
                                                float* __restrict__ rowC){
  __shared__ int hist[NEXP];
  __shared__ int fill[NEXP];
  const int tid = threadIdx.x;
  if (tid < NEXP) hist[tid] = 0;
  __syncthreads();
  int myE[NSLOT / 1024];
  #pragma unroll
  for (int p = 0; p < NSLOT / 1024; p++){
    myE[p] = ei[tid + p * 1024];
    atomicAdd(&hist[myE[p]], 1);
  }
  __syncthreads();
  if (tid == 0){
    int acc = 0;
    for (int e = 0; e < NEXP; e++){
      offsets[e] = acc; counts[e] = hist[e]; fill[e] = acc; acc += hist[e];
    }
  }
  __syncthreads();
  #pragma unroll
  for (int p = 0; p < NSLOT / 1024; p++){
    int i = tid + p * 1024;
    int slot = atomicAdd(&fill[myE[p]], 1);
    rowT[slot] = i >> 1;       // token index (i = t*TOPK + k)
    rowC[slot] = ew[i];
  }
}

__global__ void k_gather(const float* __restrict__ x, const int* __restrict__ rowT,
                         unsigned short* __restrict__ Xg){
  int slot = blockIdx.x;
  int t = rowT[slot];
  int c = threadIdx.x * 4;
  float4 v = *(const float4*)(x + (size_t)t * HSZ + c);
  ushort4 o;
  o.x = f2bf(v.x); o.y = f2bf(v.y); o.z = f2bf(v.z); o.w = f2bf(v.w);
  *(ushort4*)(Xg + (size_t)slot * HSZ + c) = o;
}

// ------- merged weight transform: fp32 [R][C] -> bf16 [C][R], w1 & w2 -------
__global__ __launch_bounds__(256) void k_transpose2(const float* __restrict__ w1,
                                                    const float* __restrict__ w2,
                                                    unsigned short* __restrict__ Wt1,
                                                    unsigned short* __restrict__ Wt2){
  __shared__ unsigned short tile[64][65];
  const int tid = threadIdx.x;
  int z = blockIdx.y;
  const float* src; unsigned short* dst; int R, C, r0, c0;
  if (z < NEXP){
    src = w1 + (size_t)z * HSZ * FFND; dst = Wt1 + (size_t)z * HSZ * FFND;
    R = HSZ; C = FFND;
    c0 = (blockIdx.x & 63) * 64; r0 = (blockIdx.x >> 6) * 64;
  } else {
    z -= NEXP;
    src = w2 + (size_t)z * FFND * HSZ; dst = Wt2 + (size_t)z * FFND * HSZ;
    R = FFND; C = HSZ;
    c0 = (blockIdx.x & 15) * 64; r0 = (blockIdx.x >> 4) * 64;
  }
  #pragma unroll
  for (int p = 0; p < 4; p++){
    int r  = p * 16 + (tid >> 4);
    int cc = (tid & 15) * 4;
    float4 v = *(const float4*)(src + (size_t)(r0 + r) * C + c0 + cc);
    tile[r][cc]   = f2bf(v.x);
    tile[r][cc+1] = f2bf(v.y);
    tile[r][cc+2] = f2bf(v.z);
    tile[r][cc+3] = f2bf(v.w);
  }
  __syncthreads();
  #pragma unroll
  for (int p = 0; p < 4; p++){
    int c  = p * 16 + (tid >> 4);
    int rr = (tid & 15) * 4;
    ushort4 o;
    o.x = tile[rr][c]; o.y = tile[rr+1][c]; o.z = tile[rr+2][c]; o.w = tile[rr+3][c];
    *(ushort4*)(dst + (size_t)(c0 + c) * R + r0 + rr) = o;
  }
}

// ---------------- GEMM core: BK=64 as two BK=32 sub-tiles ----------------
// A: bf16 [rows x K] k-contiguous, lda elems. B: bf16 [BN-slice x K] k-contig
// (pre-offset to row n0 / k-base), ldb elems. Sub-tile h of X lives at
// Xs + h*(rows*32), each [rows][32] contiguous (64B rows -> free 2-way banks,
// global_load_lds-compatible). 4 waves as 2(m) x 2(n); JF n-frags/wave; BN=32*JF.
template<int JF>
__device__ inline void gemm_core(const unsigned short* __restrict__ Ag, int lda, int rows,
                                 const unsigned short* __restrict__ Bg, int ldb, int K,
                                 unsigned short* As, unsigned short* Bs,
                                 f32x4 acc[4][JF])
{
  const int BNt  = 32 * JF;
  const int tid  = threadIdx.x;
  const int lane = tid & 63;
  const int wid  = tid >> 6;
  const int wm   = (wid & 1) * 64;
  const int wn   = (wid >> 1) * (16 * JF);
  const int q    = lane >> 4;
  const int l16  = lane & 15;
  const int rl   = lane >> 2;   // 0..15: row within 16-row group
  const int cl   = lane & 3;    // 16B chunk within 32-elem half

  for (int k0 = 0; k0 < K; k0 += BK){
    // A: wave w stages rows [w*32, w*32+32), 2 groups x 2 k-halves
    #pragma unroll
    for (int h = 0; h < 2; h++)
      #pragma unroll
      for (int p = 0; p < 2; p++){
        int r0 = wid * 32 + p * 16;
        int gr = min(r0 + rl, rows - 1);        // clamp tail (epilogue masks)
        async_copy16(Ag + (size_t)gr * lda + k0 + h * 32 + cl * 8,
                     As + h * (BM * 32) + r0 * 32);
      }
    // B: wave w stages rows [w*(BN/4), ...)
    #pragma unroll
    for (int h = 0; h < 2; h++)
      #pragma unroll
      for (int p = 0; p < BNt / 64; p++){
        int r0 = wid * (BNt / 4) + p * 16;
        async_copy16(Bg + (size_t)(r0 + rl) * ldb + k0 + h * 32 + cl * 8,
                     Bs + h * (BNt * 32) + r0 * 32);
      }
    __syncthreads();   // drains vmcnt before LDS use

    short8 af[4][2], bfr[JF][2];
    #pragma unroll
    for (int h = 0; h < 2; h++){
      #pragma unroll
      for (int i = 0; i < 4; i++)
        af[i][h] = *(const short8*)(As + h * (BM * 32) + (wm + i * 16 + l16) * 32 + q * 8);
      #pragma unroll
      for (int j = 0; j < JF; j++)
        bfr[j][h] = *(const short8*)(Bs + h * (BNt * 32) + (wn + j * 16 + l16) * 32 + q * 8);
    }
    #pragma unroll
    for (int h = 0; h < 2; h++)
      #pragma unroll
      for (int i = 0; i < 4; i++)
        #pragma unroll
        for (int j = 0; j < JF; j++)
          acc[i][j] = __builtin_amdgcn_mfma_f32_16x16x32_bf16(af[i][h], bfr[j][h], acc[i][j], 0, 0, 0);
    __syncthreads();
  }
}

// ---------------- GEMM1: H = gelu(Xg @ Wt1[e]^T), 128x128 tile ----------------
__global__ __launch_bounds__(256) void k_gemm1(const unsigned short* __restrict__ Xg,
                                               const unsigned short* __restrict__ Wt1,
                                               unsigned short* __restrict__ H,
                                               const int* __restrict__ counts,
                                               const int* __restrict__ offsets)
{
  __shared__ unsigned short smem[BM * BK + 128 * BK];   // As | Bs (32 KB)
  unsigned short* As = smem;
  unsigned short* Bs = smem + BM * BK;
  const int e    = blockIdx.z;
  const int cnt  = counts[e];
  const int mblk = blockIdx.y;
  if (mblk * BM >= cnt) return;
  const int n0   = blockIdx.x * 128;
  const int row0 = offsets[e] + mblk * BM;
  const int rows = min(BM, cnt - mblk * BM);

  f32x4 acc[4][4] = {};
  gemm_core<4>(Xg + (size_t)row0 * HSZ, HSZ, rows,
               Wt1 + (size_t)e * HSZ * FFND + (size_t)n0 * HSZ, HSZ, HSZ, As, Bs, acc);

  const int lane = threadIdx.x & 63, wid = threadIdx.x >> 6;
  const int wm = (wid & 1) * 64, wn = (wid >> 1) * 64;
  const int q = lane >> 4, l16 = lane & 15;

  // per-wave LDS repack: 16x64 bf16 subtile (stride 68), b128 readback,
  // dwordx4 global stores. Scratch is wave-private, reuses As region.
  unsigned short* scr = smem + wid * (16 * 68);
  #pragma unroll
  for (int i = 0; i < 4; i++){
    #pragma unroll
    for (int j = 0; j < 4; j++)
      #pragma unroll
      for (int r = 0; r < 4; r++)
        scr[(q * 4 + r) * 68 + j * 16 + l16] = f2bf(gelu_tanh(acc[i][j][r]));
    #pragma unroll
    for (int p = 0; p < 2; p++){
      int rr = p * 8 + (lane >> 3);
      int cc = (lane & 7) * 8;
      short8 v = *(const short8*)(scr + rr * 68 + cc);
      int grow = wm + i * 16 + rr;
      if (grow < rows)
        *(short8*)(H + (size_t)(row0 + grow) * FFND + n0 + wn + cc) = v;
    }
  }
}

// ------- GEMM2: out[t] += coef * (H @ Wt2[e]^T), 128x64 tile -------
__global__ __launch_bounds__(256) void k_gemm2(const unsigned short* __restrict__ H,
                                               const unsigned short* __restrict__ Wt2,
                                               float* __restrict__ out,
                                               const int* __restrict__ counts,
                                               const int* __restrict__ offsets,
                                               const int* __restrict__ rowT,
                                               const float* __restrict__ rowC)
{
  __shared__ unsigned short As[BM * BK];     // 16 KB
  __shared__ unsigned short Bs[64 * BK];     // 8 KB
  const int e    = blockIdx.z;
  const int cnt  = counts[e];
  const int mblk = blockIdx.y;
  if (mblk * BM >= cnt) return;
  const int n0   = blockIdx.x * 64;
  const int row0 = offsets[e] + mblk * BM;
  const int rows = min(BM, cnt - mblk * BM);

  f32x4 acc[4][2] = {};
  gemm_core<2>(H + (size_t)row0 * FFND, FFND, rows,
               Wt2 + (size_t)e * FFND * HSZ + (size_t)n0 * FFND, FFND, FFND, As, Bs, acc);

  const int lane = threadIdx.x & 63, wid = threadIdx.x >> 6;
  const int wm = (wid & 1) * 64, wn = (wid >> 1) * 32;
  const int q = lane >> 4, l16 = lane & 15;
  #pragma unroll
  for (int i = 0; i < 4; i++)
    #pragma unroll
    for (int j = 0; j < 2; j++)
      #pragma unroll
      for (int r = 0; r < 4; r++){
        int row = wm + i * 16 + q * 4 + r;
        if (row < rows){
          int g = row0 + row;
          int col = wn + j * 16 + l16;
          atomicAdd(out + (size_t)rowT[g] * HSZ + n0 + col, rowC[g] * acc[i][j][r]);
        }
      }
}

// ---------------- launch ----------------
static inline size_t align_up(size_t v, size_t a){ return (v + a - 1) & ~(a - 1); }

extern "C" void kernel_launch(void* const* d_in, const int* in_sizes, int n_in,
                              void* d_out, int out_size, void* d_ws, size_t ws_size,
                              hipStream_t stream) {
  const float* x  = (const float*)d_in[0];
  const float* ew = (const float*)d_in[1];
  const int*   ei = (const int*)d_in[2];
  const float* w1 = (const float*)d_in[3];
  const float* w2 = (const float*)d_in[4];
  float* out = (float*)d_out;

  // workspace layout (bytes)
  char* base = (char*)d_ws;
  size_t off = 0;
  int* counts  = (int*)(base + off); off += 64;
  int* offsets = (int*)(base + off); off = align_up(off + 64, 4096);
  int* rowT    = (int*)(base + off); off += (size_t)NSLOT * 4;
  float* rowC  = (float*)(base + off); off = align_up(off + (size_t)NSLOT * 4, 1 << 20);
  unsigned short* Xg  = (unsigned short*)(base + off); off = align_up(off + (size_t)NSLOT * HSZ * 2, 1 << 20);
  unsigned short* H   = (unsigned short*)(base + off); off = align_up(off + (size_t)NSLOT * FFND * 2, 1 << 20);
  unsigned short* Wt1 = (unsigned short*)(base + off); off = align_up(off + (size_t)NEXP * HSZ * FFND * 2, 1 << 20);
  unsigned short* Wt2 = (unsigned short*)(base + off); off += (size_t)NEXP * FFND * HSZ * 2;
  (void)ws_size;

  hipMemsetAsync(d_out, 0, (size_t)out_size * sizeof(float), stream);

  k_route <<<1, 1024, 0, stream>>>(ei, ew, counts, offsets, rowT, rowC);
  k_gather<<<NSLOT, 256, 0, stream>>>(x, rowT, Xg);

  // merged weight transform: z<8 -> w1 [HSZ][FFND]->Wt1; z>=8 -> w2 -> Wt2
  k_transpose2<<<dim3(1024, 2 * NEXP), 256, 0, stream>>>(w1, w2, Wt1, Wt2);

  // worst case one expert owns all 8192 rows -> 64 m-blocks; extras early-exit
  k_gemm1<<<dim3(FFND / 128, 64, NEXP), 256, 0, stream>>>(Xg, Wt1, H, counts, offsets);
  k_gemm2<<<dim3(HSZ / 64, 64, NEXP), 256, 0, stream>>>(H, Wt2, out, counts, offsets, rowT, rowC);
}

// Round 5
// 616.656 us; speedup vs baseline: 1.1361x; 1.0215x over previous
//
#include <hip/hip_runtime.h>
#include <stdint.h>

#define SLEN 2048
#define BSZ  2
#define HSZ  1024
#define FFND 4096
#define NEXP 8
#define TOPK 2
#define NTOK (SLEN*BSZ)        // 4096
#define NSLOT (NTOK*TOPK)      // 8192

#define BM 128
#define BN 128
#define BK 32
#define STAGE (BM * BK)        // 4096 shorts per operand per stage

using short8 = __attribute__((ext_vector_type(8))) short;
using f32x4  = __attribute__((ext_vector_type(4))) float;

typedef __attribute__((address_space(1))) const unsigned int gu32;
typedef __attribute__((address_space(3))) unsigned int lu32;

__device__ inline void async_copy16(const void* g, void* l){
  // DMA 16B/lane global->LDS; LDS dest = wave-uniform base + lane*16
  __builtin_amdgcn_global_load_lds((gu32*)g, (lu32*)l, 16, 0, 0);
}

__device__ inline unsigned short f2bf(float f){
  unsigned u = __builtin_bit_cast(unsigned, f);
  u += 0x7FFFu + ((u >> 16) & 1u);      // round-to-nearest-even
  return (unsigned short)(u >> 16);
}

__device__ inline float gelu_tanh(float x){
  // jax.nn.gelu default (approximate=True)
  float u = 0.7978845608028654f * (x + 0.044715f * x * x * x);
  return 0.5f * x * (1.0f + tanhf(u));
}

// ---------------- fused routing: count + scan + assign (one block) ----------
__global__ __launch_bounds__(1024) void k_route(const int* __restrict__ ei,
                                                const float* __restrict__ ew,
                                                int* __restrict__ counts,
                                                int* __restrict__ offsets,
                                                int* __restrict__ rowT,
                                                float* __restrict__ rowC){
  __shared__ int hist[NEXP];
  __shared__ int fill[NEXP];
  const int tid = threadIdx.x;
  if (tid < NEXP) hist[tid] = 0;
  __syncthreads();
  int myE[NSLOT / 1024];
  #pragma unroll
  for (int p = 0; p < NSLOT / 1024; p++){
    myE[p] = ei[tid + p * 1024];
    atomicAdd(&hist[myE[p]], 1);
  }
  __syncthreads();
  if (tid == 0){
    int acc = 0;
    for (int e = 0; e < NEXP; e++){
      offsets[e] = acc; counts[e] = hist[e]; fill[e] = acc; acc += hist[e];
    }
  }
  __syncthreads();
  #pragma unroll
  for (int p = 0; p < NSLOT / 1024; p++){
    int i = tid + p * 1024;
    int slot = atomicAdd(&fill[myE[p]], 1);
    rowT[slot] = i >> 1;       // token index (i = t*TOPK + k)
    rowC[slot] = ew[i];
  }
}

__global__ void k_gather(const float* __restrict__ x, const int* __restrict__ rowT,
                         unsigned short* __restrict__ Xg){
  int slot = blockIdx.x;
  int t = rowT[slot];
  int c = threadIdx.x * 4;
  float4 v = *(const float4*)(x + (size_t)t * HSZ + c);
  ushort4 o;
  o.x = f2bf(v.x); o.y = f2bf(v.y); o.z = f2bf(v.z); o.w = f2bf(v.w);
  *(ushort4*)(Xg + (size_t)slot * HSZ + c) = o;
}

// ------- merged weight transform: fp32 [R][C] -> bf16 [C][R], w1 & w2 -------
__global__ __launch_bounds__(256) void k_transpose2(const float* __restrict__ w1,
                                                    const float* __restrict__ w2,
                                                    unsigned short* __restrict__ Wt1,
                                                    unsigned short* __restrict__ Wt2){
  __shared__ unsigned short tile[64][65];
  const int tid = threadIdx.x;
  int z = blockIdx.y;
  const float* src; unsigned short* dst; int R, C, r0, c0;
  if (z < NEXP){
    src = w1 + (size_t)z * HSZ * FFND; dst = Wt1 + (size_t)z * HSZ * FFND;
    R = HSZ; C = FFND;
    c0 = (blockIdx.x & 63) * 64; r0 = (blockIdx.x >> 6) * 64;
  } else {
    z -= NEXP;
    src = w2 + (size_t)z * FFND * HSZ; dst = Wt2 + (size_t)z * FFND * HSZ;
    R = FFND; C = HSZ;
    c0 = (blockIdx.x & 15) * 64; r0 = (blockIdx.x >> 4) * 64;
  }
  #pragma unroll
  for (int p = 0; p < 4; p++){
    int r  = p * 16 + (tid >> 4);
    int cc = (tid & 15) * 4;
    float4 v = *(const float4*)(src + (size_t)(r0 + r) * C + c0 + cc);
    tile[r][cc]   = f2bf(v.x);
    tile[r][cc+1] = f2bf(v.y);
    tile[r][cc+2] = f2bf(v.z);
    tile[r][cc+3] = f2bf(v.w);
  }
  __syncthreads();
  #pragma unroll
  for (int p = 0; p < 4; p++){
    int c  = p * 16 + (tid >> 4);
    int rr = (tid & 15) * 4;
    ushort4 o;
    o.x = tile[rr][c]; o.y = tile[rr+1][c]; o.z = tile[rr+2][c]; o.w = tile[rr+3][c];
    *(ushort4*)(dst + (size_t)(c0 + c) * R + r0 + rr) = o;
  }
}

// -------- GEMM core: double-buffered LDS, 1 barrier/iter, async prefetch ----
// A: bf16 [rows x K] k-contiguous, lda elems. B: bf16 [128 x K] k-contiguous
// (pre-offset to row n0), ldb elems. LDS: As/Bs each 2 stages x [128][32]
// unpadded. stage(k+1) issued AFTER the barrier publishing stage k, so its
// DMA latency overlaps compute(k); it is drained at the NEXT barrier.
__device__ inline void gemm_core(const unsigned short* __restrict__ Ag, int lda, int rows,
                                 const unsigned short* __restrict__ Bg, int ldb, int K,
                                 unsigned short* As, unsigned short* Bs,
                                 f32x4 acc[4][4])
{
  const int tid  = threadIdx.x;
  const int lane = tid & 63;
  const int wid  = tid >> 6;
  const int wm   = (wid & 1) * 64;
  const int wn   = (wid >> 1) * 64;
  const int q    = lane >> 4;
  const int l16  = lane & 15;

  // stage tile at k-offset k0 into stage s
  auto stage = [&](int k0, int s){
    #pragma unroll
    for (int p = 0; p < 2; p++){
      int c  = (wid * 2 + p) * 64 + lane;   // chunk id, 16B each
      int r  = c >> 2;
      int kp = (c & 3) * 8;
      int ra = min(r, rows - 1);            // clamp tail (epilogue masks)
      async_copy16(Ag + (size_t)ra * lda + k0 + kp, As + s * STAGE + (wid * 2 + p) * 512);
      async_copy16(Bg + (size_t)r  * ldb + k0 + kp, Bs + s * STAGE + (wid * 2 + p) * 512);
    }
  };

  const int niter = K / BK;
  stage(0, 0);
  for (int k = 0; k < niter; k++){
    __syncthreads();                       // drains stage(k) copies; publishes buf[k&1]
    if (k + 1 < niter) stage((k + 1) * BK, (k + 1) & 1);  // in flight during compute(k)
    const unsigned short* Ak = As + (k & 1) * STAGE;
    const unsigned short* Bk = Bs + (k & 1) * STAGE;

    short8 af[4], bfr[4];
    #pragma unroll
    for (int i = 0; i < 4; i++)
      af[i] = *(const short8*)(Ak + (wm + i * 16 + l16) * BK + q * 8);
    #pragma unroll
    for (int j = 0; j < 4; j++)
      bfr[j] = *(const short8*)(Bk + (wn + j * 16 + l16) * BK + q * 8);

    #pragma unroll
    for (int i = 0; i < 4; i++)
      #pragma unroll
      for (int j = 0; j < 4; j++)
        acc[i][j] = __builtin_amdgcn_mfma_f32_16x16x32_bf16(af[i], bfr[j], acc[i][j], 0, 0, 0);
  }
}

// ---------------- GEMM1: H = gelu(Xg @ Wt1[e]^T), 128x128 tile --------------
__global__ __launch_bounds__(256) void k_gemm1(const unsigned short* __restrict__ Xg,
                                               const unsigned short* __restrict__ Wt1,
                                               unsigned short* __restrict__ H,
                                               const int* __restrict__ counts,
                                               const int* __restrict__ offsets)
{
  __shared__ unsigned short smem[4 * STAGE];   // As(2 stages) | Bs(2 stages) = 32 KB
  unsigned short* As = smem;
  unsigned short* Bs = smem + 2 * STAGE;
  const int e    = blockIdx.z;
  const int cnt  = counts[e];
  const int mblk = blockIdx.y;
  if (mblk * BM >= cnt) return;
  const int n0   = blockIdx.x * BN;
  const int row0 = offsets[e] + mblk * BM;
  const int rows = min(BM, cnt - mblk * BM);

  f32x4 acc[4][4] = {};
  gemm_core(Xg + (size_t)row0 * HSZ, HSZ, rows,
            Wt1 + (size_t)e * HSZ * FFND + (size_t)n0 * HSZ, HSZ, HSZ, As, Bs, acc);
  __syncthreads();   // all compute reads done before reusing smem as scratch

  const int lane = threadIdx.x & 63, wid = threadIdx.x >> 6;
  const int wm = (wid & 1) * 64, wn = (wid >> 1) * 64;
  const int q = lane >> 4, l16 = lane & 15;

  // per-wave LDS repack: 16x64 bf16 subtile (stride 68), b128 readback,
  // dwordx4 global stores. Scratch is wave-private.
  unsigned short* scr = smem + wid * (16 * 68);
  #pragma unroll
  for (int i = 0; i < 4; i++){
    #pragma unroll
    for (int j = 0; j < 4; j++)
      #pragma unroll
      for (int r = 0; r < 4; r++)
        scr[(q * 4 + r) * 68 + j * 16 + l16] = f2bf(gelu_tanh(acc[i][j][r]));
    #pragma unroll
    for (int p = 0; p < 2; p++){
      int rr = p * 8 + (lane >> 3);
      int cc = (lane & 7) * 8;
      short8 v = *(const short8*)(scr + rr * 68 + cc);
      int grow = wm + i * 16 + rr;
      if (grow < rows)
        *(short8*)(H + (size_t)(row0 + grow) * FFND + n0 + wn + cc) = v;
    }
  }
}

// ------- GEMM2: out[t] += coef * (H @ Wt2[e]^T), 128x128 tile -------
__global__ __launch_bounds__(256) void k_gemm2(const unsigned short* __restrict__ H,
                                               const unsigned short* __restrict__ Wt2,
                                               float* __restrict__ out,
                                               const int* __restrict__ counts,
                                               const int* __restrict__ offsets,
                                               const int* __restrict__ rowT,
                                               const float* __restrict__ rowC)
{
  __shared__ unsigned short smem[4 * STAGE];   // 32 KB
  unsigned short* As = smem;
  unsigned short* Bs = smem + 2 * STAGE;
  const int e    = blockIdx.z;
  const int cnt  = counts[e];
  const int mblk = blockIdx.y;
  if (mblk * BM >= cnt) return;
  const int n0   = blockIdx.x * BN;
  const int row0 = offsets[e] + mblk * BM;
  const int rows = min(BM, cnt - mblk * BM);

  f32x4 acc[4][4] = {};
  gemm_core(H + (size_t)row0 * FFND, FFND, rows,
            Wt2 + (size_t)e * FFND * HSZ + (size_t)n0 * FFND, FFND, FFND, As, Bs, acc);

  const int lane = threadIdx.x & 63, wid = threadIdx.x >> 6;
  const int wm = (wid & 1) * 64, wn = (wid >> 1) * 64;
  const int q = lane >> 4, l16 = lane & 15;
  #pragma unroll
  for (int i = 0; i < 4; i++)
    #pragma unroll
    for (int j = 0; j < 4; j++)
      #pragma unroll
      for (int r = 0; r < 4; r++){
        int row = wm + i * 16 + q * 4 + r;
        if (row < rows){
          int g = row0 + row;
          int col = wn + j * 16 + l16;
          atomicAdd(out + (size_t)rowT[g] * HSZ + n0 + col, rowC[g] * acc[i][j][r]);
        }
      }
}

// ---------------- launch ----------------
static inline size_t align_up(size_t v, size_t a){ return (v + a - 1) & ~(a - 1); }

extern "C" void kernel_launch(void* const* d_in, const int* in_sizes, int n_in,
                              void* d_out, int out_size, void* d_ws, size_t ws_size,
                              hipStream_t stream) {
  const float* x  = (const float*)d_in[0];
  const float* ew = (const float*)d_in[1];
  const int*   ei = (const int*)d_in[2];
  const float* w1 = (const float*)d_in[3];
  const float* w2 = (const float*)d_in[4];
  float* out = (float*)d_out;

  // workspace layout (bytes)
  char* base = (char*)d_ws;
  size_t off = 0;
  int* counts  = (int*)(base + off); off += 64;
  int* offsets = (int*)(base + off); off = align_up(off + 64, 4096);
  int* rowT    = (int*)(base + off); off += (size_t)NSLOT * 4;
  float* rowC  = (float*)(base + off); off = align_up(off + (size_t)NSLOT * 4, 1 << 20);
  unsigned short* Xg  = (unsigned short*)(base + off); off = align_up(off + (size_t)NSLOT * HSZ * 2, 1 << 20);
  unsigned short* H   = (unsigned short*)(base + off); off = align_up(off + (size_t)NSLOT * FFND * 2, 1 << 20);
  unsigned short* Wt1 = (unsigned short*)(base + off); off = align_up(off + (size_t)NEXP * HSZ * FFND * 2, 1 << 20);
  unsigned short* Wt2 = (unsigned short*)(base + off); off += (size_t)NEXP * FFND * HSZ * 2;
  (void)ws_size;

  hipMemsetAsync(d_out, 0, (size_t)out_size * sizeof(float), stream);

  k_route <<<1, 1024, 0, stream>>>(ei, ew, counts, offsets, rowT, rowC);
  k_gather<<<NSLOT, 256, 0, stream>>>(x, rowT, Xg);

  // merged weight transform: z<8 -> w1 [HSZ][FFND]->Wt1; z>=8 -> w2 -> Wt2
  k_transpose2<<<dim3(1024, 2 * NEXP), 256, 0, stream>>>(w1, w2, Wt1, Wt2);

  // worst case one expert owns all 8192 rows -> 64 m-blocks; extras early-exit
  k_gemm1<<<dim3(FFND / BN, 64, NEXP), 256, 0, stream>>>(Xg, Wt1, H, counts, offsets);
  k_gemm2<<<dim3(HSZ / BN, 64, NEXP), 256, 0, stream>>>(H, Wt2, out, counts, offsets, rowT, rowC);
}